// Round 1
// baseline (43.560 us; speedup 1.0000x reference)
//
#include <hip/hip_runtime.h>

// out[j] = sum_i alpha[i] * T[lab_obs[i], lab_x[j]] * matern52(xobs[i], x[j]; ls)
// N = M = 8192, D = 8, ND = 4 (domains contiguous, 2048-aligned).

#define BLOCK 256
#define CPT 4     // columns per thread -> 1024-column tile per block
#define RPC 64    // rows per chunk
#define DPT 8     // feature dim (fixed by the model)
#define MAXT 81   // (ND+1)^2 with ND<=8

__global__ __launch_bounds__(BLOCK) void matern_mv_kernel(
    const float* __restrict__ x,      // [M][8]
    const float* __restrict__ xobs,   // [N][8]
    const float* __restrict__ alpha,  // [N]
    const float* __restrict__ tfl,    // [ND*(ND-1)/2]
    const float* __restrict__ ls,     // [1]
    const int*  __restrict__ dro,     // [ND][2]
    const int*  __restrict__ drx,     // [ND][2]
    float* __restrict__ out,          // [M]
    int M, int N, int ND)
{
    __shared__ float T[MAXT];
    __shared__ float rowbuf[RPC][12];  // [0..7]=-2/ls^2 * xobs, [8]=na, [9]=alpha*w

    const int tid      = threadIdx.x;
    const int colBase  = blockIdx.x * (BLOCK * CPT);
    const int rowBase  = blockIdx.y * RPC;
    const int tdim     = ND + 1;

    const float rls  = 1.0f / ls[0];
    const float rls2 = rls * rls;

    // ---- build T (transfer-factor matrix) in LDS ----
    if (tid < tdim * tdim) T[tid] = 1.0f;
    __syncthreads();
    if (tid == 0) {
        int n = 0;
        for (int i = 0; i < ND; ++i)
            for (int j = i + 1; j < ND; ++j) {
                float v = 1.0f / (1.0f + __expf(-tfl[n]));
                T[i * tdim + j] = v;
                T[j * tdim + i] = v;
                ++n;
            }
    }
    __syncthreads();

    // ---- block-uniform column-domain label (tile lies inside one domain) ----
    int labj = ND;
    for (int d = 0; d < ND; ++d)
        if (colBase >= drx[2 * d] && colBase < drx[2 * d + 1]) labj = d;

    // ---- stage row chunk into LDS ----
    const float m2rls2 = -2.0f * rls2;
    for (int r = tid; r < RPC; r += BLOCK) {
        int i = rowBase + r;
        if (i < N) {
            float na = 0.0f;
            float av[DPT];
            #pragma unroll
            for (int k = 0; k < DPT; ++k) {
                float v = xobs[i * DPT + k];
                av[k] = v;
                na += v * v;
            }
            #pragma unroll
            for (int k = 0; k < DPT; ++k) rowbuf[r][k] = av[k] * m2rls2;
            rowbuf[r][8] = na * rls2;
            int labi = ND;
            for (int d = 0; d < ND; ++d)
                if (i >= dro[2 * d] && i < dro[2 * d + 1]) labi = d;
            rowbuf[r][9] = alpha[i] * T[labi * tdim + labj];
        } else {
            rowbuf[r][8] = 0.0f;
            rowbuf[r][9] = 0.0f;   // aw=0 -> contributes nothing
            #pragma unroll
            for (int k = 0; k < DPT; ++k) rowbuf[r][k] = 0.0f;
        }
    }

    // ---- load this thread's columns (raw x, scaling folded into rows) ----
    float b[CPT][DPT];
    float nb[CPT], acc[CPT];
    int   jj[CPT];
    #pragma unroll
    for (int c = 0; c < CPT; ++c) {
        int j = colBase + c * BLOCK + tid;
        jj[c] = j;
        float s2 = 0.0f;
        if (j < M) {
            #pragma unroll
            for (int k = 0; k < DPT; ++k) {
                float v = x[j * DPT + k];
                b[c][k] = v;
                s2 += v * v;
            }
        } else {
            #pragma unroll
            for (int k = 0; k < DPT; ++k) b[c][k] = 0.0f;
        }
        nb[c]  = s2 * rls2;
        acc[c] = 0.0f;
    }
    __syncthreads();

    // ---- main loop: 64 rows x 4 columns per thread ----
    const float SQRT5 = 2.23606797749979f;
    const float C13   = 0.3333333333333333f;
    const int rmax = min(RPC, N - rowBase);
    for (int r = 0; r < rmax; ++r) {
        float a0 = rowbuf[r][0], a1 = rowbuf[r][1], a2 = rowbuf[r][2], a3 = rowbuf[r][3];
        float a4 = rowbuf[r][4], a5 = rowbuf[r][5], a6 = rowbuf[r][6], a7 = rowbuf[r][7];
        float na = rowbuf[r][8], aw = rowbuf[r][9];
        #pragma unroll
        for (int c = 0; c < CPT; ++c) {
            float sq = na + nb[c];
            sq = fmaf(a0, b[c][0], sq);
            sq = fmaf(a1, b[c][1], sq);
            sq = fmaf(a2, b[c][2], sq);
            sq = fmaf(a3, b[c][3], sq);
            sq = fmaf(a4, b[c][4], sq);
            sq = fmaf(a5, b[c][5], sq);
            sq = fmaf(a6, b[c][6], sq);
            sq = fmaf(a7, b[c][7], sq);
            sq = fmaxf(sq, 1e-12f);
            float dd = __builtin_amdgcn_sqrtf(sq);
            float s  = SQRT5 * dd;
            float e  = __expf(-s);
            float p  = fmaf(s, fmaf(s, C13, 1.0f), 1.0f);
            acc[c]   = fmaf(p * e, aw, acc[c]);
        }
    }

    // ---- accumulate partial sums ----
    #pragma unroll
    for (int c = 0; c < CPT; ++c)
        if (jj[c] < M) atomicAdd(&out[jj[c]], acc[c]);
}

extern "C" void kernel_launch(void* const* d_in, const int* in_sizes, int n_in,
                              void* d_out, int out_size, void* d_ws, size_t ws_size,
                              hipStream_t stream) {
    const float* x     = (const float*)d_in[0];
    const float* xobs  = (const float*)d_in[1];
    const float* alpha = (const float*)d_in[2];
    const float* tfl   = (const float*)d_in[3];
    const float* ls    = (const float*)d_in[4];
    const int*   dro   = (const int*)d_in[5];
    const int*   drx   = (const int*)d_in[6];
    float* out = (float*)d_out;

    const int M  = in_sizes[0] / DPT;
    const int N  = in_sizes[1] / DPT;
    const int ND = in_sizes[5] / 2;

    hipMemsetAsync(d_out, 0, (size_t)M * sizeof(float), stream);

    dim3 grid((M + BLOCK * CPT - 1) / (BLOCK * CPT), (N + RPC - 1) / RPC);
    matern_mv_kernel<<<grid, dim3(BLOCK), 0, stream>>>(
        x, xobs, alpha, tfl, ls, dro, drx, out, M, N, ND);
}

// Round 2
// 43.004 us; speedup vs baseline: 1.0129x; 1.0129x over previous
//
#include <hip/hip_runtime.h>

// out[j] = sum_i alpha[i] * T[lab_obs[i], lab_x[j]] * matern52(xobs[i], x[j]; ls)
// N = M = 8192, D = 8, ND = 4 (domains contiguous, 2048-aligned).
//
// MFMA formulation: sq_ij = na_i + nb_j + dot(ahat_i, b_j) computed by
// mfma_f32_16x16x32_bf16 with C seeded to na_i+nb_j and the K dimension
// packed as split-bf16: A = [ahi(8) | alo(8) | ahi(8) | x], B = [bhi | bhi | blo | 0].

typedef __attribute__((ext_vector_type(8))) short  short8v;  // bf16x8 frag
typedef __attribute__((ext_vector_type(4))) float  f32x4;    // C/D frag
typedef __attribute__((ext_vector_type(4))) unsigned int u32x4;

#define BLOCK       256
#define STAGE_ROWS  128
#define ROWS_PER_BLOCK 512
#define RSTRIDE     20      // floats per staged row (80 B: 2-way-max LDS conflicts)
#define DPT         8

__global__ __launch_bounds__(BLOCK) void matern_mfma_kernel(
    const float* __restrict__ x,      // [M][8]
    const float* __restrict__ xobs,   // [N][8]
    const float* __restrict__ alpha,  // [N]
    const float* __restrict__ tfl,    // [ND*(ND-1)/2]
    const float* __restrict__ ls,     // [1]
    const int*  __restrict__ dro,     // [ND][2]
    const int*  __restrict__ drx,     // [ND][2]
    float* __restrict__ out,          // [M]
    int M, int N, int ND)
{
    __shared__ __align__(16) float rowbuf[STAGE_ROWS * RSTRIDE];

    const int tid  = threadIdx.x;
    const int wave = tid >> 6;
    const int lane = tid & 63;
    const int g    = lane >> 4;     // k-group / D-row group
    const int r15  = lane & 15;     // A row within tile / D,B column

    const float rls    = 1.0f / ls[0];
    const float rls2   = rls * rls;
    const float m2rls2 = -2.0f * rls2;

    const int colBase = blockIdx.x * 64;
    const int rowBase = blockIdx.y * ROWS_PER_BLOCK;

    // block-uniform column-domain label (64-col tile within one domain;
    // domain edges are multiples of 2048)
    int labj = ND;
    for (int d = 0; d < ND; ++d)
        if (colBase >= drx[2 * d] && colBase < drx[2 * d + 1]) labj = d;

    // ---- per-lane column setup: B fragment + nb, held in registers ----
    const int j = colBase + wave * 16 + r15;
    float nb = 0.0f;
    short8v bfrag;
    {
        float vv[DPT];
        if (j < M) {
            float4 p0 = *(const float4*)(x + (size_t)j * DPT);
            float4 p1 = *(const float4*)(x + (size_t)j * DPT + 4);
            vv[0]=p0.x; vv[1]=p0.y; vv[2]=p0.z; vv[3]=p0.w;
            vv[4]=p1.x; vv[5]=p1.y; vv[6]=p1.z; vv[7]=p1.w;
        } else {
            #pragma unroll
            for (int k = 0; k < DPT; ++k) vv[k] = 0.0f;
        }
        unsigned int bhi[4], blo[4];
        #pragma unroll
        for (int k = 0; k < 4; ++k) {
            float a0 = vv[2*k], a1 = vv[2*k+1];
            nb += a0 * a0 + a1 * a1;
            unsigned int u0 = __builtin_bit_cast(unsigned int, a0);
            unsigned int u1 = __builtin_bit_cast(unsigned int, a1);
            unsigned int h0 = u0 & 0xffff0000u, h1 = u1 & 0xffff0000u;
            float r0 = a0 - __builtin_bit_cast(float, h0);
            float r1 = a1 - __builtin_bit_cast(float, h1);
            unsigned int l0 = __builtin_bit_cast(unsigned int, r0) >> 16;
            unsigned int l1 = __builtin_bit_cast(unsigned int, r1) >> 16;
            bhi[k] = (h0 >> 16) | (h1 & 0xffff0000u);
            blo[k] = l0 | (l1 << 16);
        }
        nb *= rls2;
        u32x4 bw;
        #pragma unroll
        for (int k = 0; k < 4; ++k)
            bw[k] = (g == 3) ? 0u : ((g == 2) ? blo[k] : bhi[k]);
        bfrag = __builtin_bit_cast(short8v, bw);
    }

    float colacc = 0.0f;
    const float SQRT5 = 2.23606797749979f;
    const float C13   = 0.3333333333333333f;

    for (int sb = 0; sb < ROWS_PER_BLOCK; sb += STAGE_ROWS) {
        __syncthreads();   // protect rowbuf from previous round's readers
        if (tid < STAGE_ROWS) {
            const int i = rowBase + sb + tid;
            float* rb = rowbuf + tid * RSTRIDE;
            if (i < N) {
                float4 p0 = *(const float4*)(xobs + (size_t)i * DPT);
                float4 p1 = *(const float4*)(xobs + (size_t)i * DPT + 4);
                float vv[DPT] = {p0.x,p0.y,p0.z,p0.w,p1.x,p1.y,p1.z,p1.w};
                float na = 0.0f;
                unsigned int hi[4], lo[4];
                #pragma unroll
                for (int k = 0; k < 4; ++k) {
                    float a0 = vv[2*k], a1 = vv[2*k+1];
                    na += a0 * a0 + a1 * a1;
                    a0 *= m2rls2; a1 *= m2rls2;
                    unsigned int u0 = __builtin_bit_cast(unsigned int, a0);
                    unsigned int u1 = __builtin_bit_cast(unsigned int, a1);
                    unsigned int h0 = u0 & 0xffff0000u, h1 = u1 & 0xffff0000u;
                    float r0 = a0 - __builtin_bit_cast(float, h0);
                    float r1 = a1 - __builtin_bit_cast(float, h1);
                    unsigned int l0 = __builtin_bit_cast(unsigned int, r0) >> 16;
                    unsigned int l1 = __builtin_bit_cast(unsigned int, r1) >> 16;
                    hi[k] = (h0 >> 16) | (h1 & 0xffff0000u);
                    lo[k] = l0 | (l1 << 16);
                }
                na *= rls2;
                int labi = ND;
                for (int d = 0; d < ND; ++d)
                    if (i >= dro[2 * d] && i < dro[2 * d + 1]) labi = d;
                float w = 1.0f;
                if (labi != labj && labi < ND && labj < ND) {
                    int a_ = min(labi, labj), b_ = max(labi, labj);
                    int n  = a_ * (2 * ND - a_ - 1) / 2 + (b_ - a_ - 1);
                    w = 1.0f / (1.0f + __expf(-tfl[n]));
                }
                *(uint4*)(rb)     = make_uint4(hi[0], hi[1], hi[2], hi[3]);
                *(uint4*)(rb + 4) = make_uint4(lo[0], lo[1], lo[2], lo[3]);
                rb[8] = na;
                rb[9] = alpha[i] * w;
            } else {
                *(uint4*)(rb)     = make_uint4(0u, 0u, 0u, 0u);
                *(uint4*)(rb + 4) = make_uint4(0u, 0u, 0u, 0u);
                rb[8] = 0.0f;
                rb[9] = 0.0f;
            }
        }
        __syncthreads();

        #pragma unroll
        for (int it = 0; it < STAGE_ROWS / 16; ++it) {
            // A fragment: row = it*16 + r15; g==1 reads lo-half, others hi
            // (g==3's A is don't-care: B k-slots 24..31 are zero)
            const float* rbA = rowbuf + (it * 16 + r15) * RSTRIDE + ((g == 1) ? 4 : 0);
            short8v afrag = *(const short8v*)rbA;

            f32x4 c;
            float awr[4];
            #pragma unroll
            for (int q = 0; q < 4; ++q) {
                const float2 nw = *(const float2*)(rowbuf + (it * 16 + g * 4 + q) * RSTRIDE + 8);
                c[q]   = nw.x + nb;   // na_i + nb_j seed
                awr[q] = nw.y;        // alpha_i * W
            }

            f32x4 acc = __builtin_amdgcn_mfma_f32_16x16x32_bf16(afrag, bfrag, c, 0, 0, 0);

            #pragma unroll
            for (int q = 0; q < 4; ++q) {
                float sq = fmaxf(acc[q], 1e-12f);
                float dd = __builtin_amdgcn_sqrtf(sq);
                float s  = SQRT5 * dd;
                float e  = __expf(-s);
                float p  = fmaf(s, fmaf(s, C13, 1.0f), 1.0f);
                colacc   = fmaf(p * e, awr[q], colacc);
            }
        }
    }

    // reduce the 4 D-row groups (lanes r15, r15+16, r15+32, r15+48)
    colacc += __shfl_xor(colacc, 16);
    colacc += __shfl_xor(colacc, 32);
    if (g == 0 && j < M) atomicAdd(&out[j], colacc);
}

extern "C" void kernel_launch(void* const* d_in, const int* in_sizes, int n_in,
                              void* d_out, int out_size, void* d_ws, size_t ws_size,
                              hipStream_t stream) {
    const float* x     = (const float*)d_in[0];
    const float* xobs  = (const float*)d_in[1];
    const float* alpha = (const float*)d_in[2];
    const float* tfl   = (const float*)d_in[3];
    const float* ls    = (const float*)d_in[4];
    const int*   dro   = (const int*)d_in[5];
    const int*   drx   = (const int*)d_in[6];
    float* out = (float*)d_out;

    const int M  = in_sizes[0] / DPT;
    const int N  = in_sizes[1] / DPT;
    const int ND = in_sizes[5] / 2;

    hipMemsetAsync(d_out, 0, (size_t)M * sizeof(float), stream);

    dim3 grid((M + 63) / 64, (N + ROWS_PER_BLOCK - 1) / ROWS_PER_BLOCK);
    matern_mfma_kernel<<<grid, dim3(BLOCK), 0, stream>>>(
        x, xobs, alpha, tfl, ls, dro, drx, out, M, N, ND);
}